// Round 2
// baseline (1138.131 us; speedup 1.0000x reference)
//
#include <hip/hip_runtime.h>
#include <stdint.h>

typedef unsigned short u16;
typedef float floatx4 __attribute__((ext_vector_type(4)));
typedef __bf16 bf16x8 __attribute__((ext_vector_type(8)));
typedef float f32x4v __attribute__((ext_vector_type(4)));
typedef unsigned u32x4v __attribute__((ext_vector_type(4)));

#define NUM_AREAS 4
#define AN 2048
#define NTOT 8192
#define BATCH 512
#define DIN 1024
#define NCLS 1024
#define THRESHOLD 0.05f
#define BAN (BATCH * AN)  // 1048576 elems per (area) slab

__device__ __forceinline__ u16 f2bf(float f) {
    union { float f; unsigned u; } v; v.f = f;
    unsigned r = v.u + 0x7fffu + ((v.u >> 16) & 1u);  // RNE
    return (u16)(r >> 16);
}

__device__ __forceinline__ void load_lds16(const u16* g, u16* l) {
    __builtin_amdgcn_global_load_lds((const __attribute__((address_space(1))) void*)g,
                                     (__attribute__((address_space(3))) void*)l,
                                     16, 0, 0);
}

// ---- 128x128 bf16 GEMM core, depth-1 double-buffered (T3 minimal 2-phase) ----
// C += A[128,klen] * B[128,klen]^T. A row-major lda, Bm row-major ldb.
// 256 threads = 4 waves in 2x2; each wave 64x64 via 4x4 tiles of 16x16x32 MFMA.
// Pipeline: STAGE(buf^1, t+1) issued BEFORE compute(buf); single barrier/iter
// whose implicit vmcnt(0) waits on loads that had a full K-step to land.
__device__ __forceinline__ void gemm_db(const u16* __restrict__ A, int lda,
                                        const u16* __restrict__ Bm, int ldb,
                                        int klen, u16* sA, u16* sB,
                                        floatx4 acc[4][4]) {
    const int tid = threadIdx.x;
    const int t8 = tid * 8;
    const int lane = tid & 63;
    const int quad = lane >> 4;
    const int l15 = lane & 15;
    const int wm = ((tid >> 7) & 1) * 64;
    const int wn = ((tid >> 6) & 1) * 64;
    const int r0 = t8 >> 5;          // rows 0..63 (q=0), +64 for q=1
    const int kk = t8 & 31;          // k offset within 32-wide tile
    const int nst = klen >> 5;

    auto stage = [&](int buf, int k0) {
        const int bo = buf << 12;    // buffer offset in elems (4096)
        load_lds16(A + (size_t)r0 * lda + (k0 + kk), sA + bo + t8);
        load_lds16(Bm + (size_t)r0 * ldb + (k0 + kk), sB + bo + t8);
        load_lds16(A + (size_t)(r0 + 64) * lda + (k0 + kk), sA + bo + 2048 + t8);
        load_lds16(Bm + (size_t)(r0 + 64) * ldb + (k0 + kk), sB + bo + 2048 + t8);
    };

    stage(0, 0);
    __syncthreads();                 // drain prologue stage
    int buf = 0;
    for (int t = 0; t < nst; ++t) {
        if (t + 1 < nst) stage(buf ^ 1, (t + 1) << 5);  // issue-early prefetch
        const int bo = buf << 12;
        bf16x8 av[4], bv[4];
#pragma unroll
        for (int i = 0; i < 4; ++i)
            av[i] = *(const bf16x8*)(sA + bo + (wm + i * 16 + l15) * 32 + quad * 8);
#pragma unroll
        for (int i = 0; i < 4; ++i)
            bv[i] = *(const bf16x8*)(sB + bo + (wn + i * 16 + l15) * 32 + quad * 8);
#pragma unroll
        for (int mt = 0; mt < 4; ++mt)
#pragma unroll
            for (int nt = 0; nt < 4; ++nt)
                acc[mt][nt] = __builtin_amdgcn_mfma_f32_16x16x32_bf16(av[mt], bv[nt], acc[mt][nt], 0, 0, 0);
        __syncthreads();             // vmcnt(0): waits prefetch; syncs buf reuse
        buf ^= 1;
    }
}

// ---- init: logits = Ob broadcast, gate accumulators = 0 ----
__global__ void k_init(const float* __restrict__ Ob, float* __restrict__ out,
                       float* __restrict__ gacc) {
    const int i = blockIdx.x * 256 + threadIdx.x;
    if (i < BATCH * NCLS) out[i] = Ob[i & (NCLS - 1)];
    if (i < 32) gacc[i] = 0.f;
}

// ---- f32 -> bf16 bulk convert (8 elems/thread) ----
__global__ void k_cvt(const float* __restrict__ src, u16* __restrict__ dst, int n8) {
    const int i = blockIdx.x * 256 + threadIdx.x;
    if (i >= n8) return;
    const float4 x0 = ((const float4*)src)[2 * i];
    const float4 x1 = ((const float4*)src)[2 * i + 1];
    uint4 o;
    o.x = (unsigned)f2bf(x0.x) | ((unsigned)f2bf(x0.y) << 16);
    o.y = (unsigned)f2bf(x0.z) | ((unsigned)f2bf(x0.w) << 16);
    o.z = (unsigned)f2bf(x1.x) | ((unsigned)f2bf(x1.y) << 16);
    o.w = (unsigned)f2bf(x1.z) | ((unsigned)f2bf(x1.w) << 16);
    ((uint4*)dst)[i] = o;
}

// ---- Weff = W * clamp(mask,0,1) -> bf16, 16 elems/thread, NT loads/stores ----
__global__ void k_weff(const float* __restrict__ W, const float* __restrict__ mask,
                       u16* __restrict__ dst) {
    const int stride = gridDim.x * 256;
    const int n16 = (16 * AN * AN) / 16;  // 4,194,304
    for (int i = blockIdx.x * 256 + threadIdx.x; i < n16; i += stride) {
        const f32x4v* wp = (const f32x4v*)W + (size_t)4 * i;
        const f32x4v* mp = (const f32x4v*)mask + (size_t)4 * i;
        u32x4v* dp = (u32x4v*)dst + (size_t)2 * i;
        f32x4v w[4], m[4];
#pragma unroll
        for (int j = 0; j < 4; ++j) w[j] = __builtin_nontemporal_load(wp + j);
#pragma unroll
        for (int j = 0; j < 4; ++j) m[j] = __builtin_nontemporal_load(mp + j);
        u32x4v o[2];
#pragma unroll
        for (int j = 0; j < 4; ++j) {
#pragma unroll
            for (int k = 0; k < 4; k += 2) {
                const float a = w[j][k] * fminf(fmaxf(m[j][k], 0.f), 1.f);
                const float b = w[j][k + 1] * fminf(fmaxf(m[j][k + 1], 0.f), 1.f);
                o[j >> 1][((j & 1) << 1) | (k >> 1)] =
                    (unsigned)f2bf(a) | ((unsigned)f2bf(b) << 16);
            }
        }
        __builtin_nontemporal_store(o[0], dp);
        __builtin_nontemporal_store(o[1], dp + 1);
    }
}

// ---- encoder: Z0 = tanh(x @ Rw^T + rb), write hist[0], z0(bf16), gate sums ----
__global__ void k_enc(const u16* __restrict__ xbf, const u16* __restrict__ rwbf,
                      const float* __restrict__ rb, float* __restrict__ hist0,
                      u16* __restrict__ z0, float* __restrict__ gacc) {
    __shared__ __align__(16) u16 smemA[8192];
    __shared__ __align__(16) u16 smemB[8192];
    __shared__ float red[4];
    floatx4 acc[4][4] = {};
    const int mb = blockIdx.y, nb = blockIdx.x;
    gemm_db(xbf + (size_t)mb * 128 * DIN, DIN,
            rwbf + (size_t)nb * 128 * DIN, DIN, DIN, smemA, smemB, acc);
    const int tid = threadIdx.x, lane = tid & 63, quad = lane >> 4, l15 = lane & 15;
    const int wm = ((tid >> 7) & 1) * 64, wn = ((tid >> 6) & 1) * 64;
    const int cbase = nb * 128;
    const int area = cbase >> 11;
    float asum = 0.f;
#pragma unroll
    for (int nt = 0; nt < 4; ++nt) {
        const int col = cbase + wn + nt * 16 + l15;
        const int n = col & (AN - 1);
        const float bias = rb[col];
#pragma unroll
        for (int mt = 0; mt < 4; ++mt) {
#pragma unroll
            for (int r = 0; r < 4; ++r) {
                const int row = mb * 128 + wm + mt * 16 + quad * 4 + r;
                const float z = tanhf(acc[mt][nt][r] + bias);
                asum += fabsf(z);
                const size_t idx = (size_t)area * BAN + (size_t)row * AN + n;
                hist0[idx] = z;
                z0[idx] = f2bf(z);
            }
        }
    }
    for (int off = 32; off > 0; off >>= 1) asum += __shfl_down(asum, off, 64);
    if (lane == 0) red[tid >> 6] = asum;
    __syncthreads();
    if (tid == 0) atomicAdd(&gacc[area], red[0] + red[1] + red[2] + red[3]);
}

// ---- tick GEMM, split-K over input areas: zacc[i][o] = Z_prev[i] @ Weff[o,i]^T ----
// grid (64 nb, 4 mb, 4 i) = 1024 blocks -> 4 blocks/CU
__global__ void k_tick_mm(const u16* __restrict__ zprev, const u16* __restrict__ weff,
                          const float* __restrict__ gin, float* __restrict__ zacc) {
    __shared__ __align__(16) u16 smemA[8192];
    __shared__ __align__(16) u16 smemB[8192];
    const int nb = blockIdx.x, mb = blockIdx.y, i = blockIdx.z;
    const float thr = THRESHOLD * (float)BAN;  // gate on mean|Z| -> compare sums
    if (!(gin[i] > thr)) return;               // block-uniform; stale slice never read
    floatx4 acc[4][4] = {};
    const int cbase = nb * 128;
    const int o = cbase >> 11;
    const int nbase = cbase & (AN - 1);
    gemm_db(zprev + (size_t)i * BAN + (size_t)mb * 128 * AN, AN,
            weff + ((size_t)(o * 4 + i) * AN + nbase) * AN, AN, AN,
            smemA, smemB, acc);
    float* __restrict__ dst = zacc + ((size_t)i * 4 + o) * BAN;
    const int tid = threadIdx.x, lane = tid & 63, quad = lane >> 4, l15 = lane & 15;
    const int wm = ((tid >> 7) & 1) * 64, wn = ((tid >> 6) & 1) * 64;
#pragma unroll
    for (int nt = 0; nt < 4; ++nt) {
        const int n = nbase + wn + nt * 16 + l15;
#pragma unroll
        for (int mt = 0; mt < 4; ++mt) {
#pragma unroll
            for (int r = 0; r < 4; ++r) {
                const int row = mb * 128 + wm + mt * 16 + quad * 4 + r;
                dst[(size_t)row * AN + n] = acc[mt][nt][r];
            }
        }
    }
}

// ---- tick epilogue: Z = tanh(sum_i gate[i]*zacc[i][o] + sum_i gate[i]*b[o,i]) ----
__global__ void k_tick_ep(const float* __restrict__ zacc, const float* __restrict__ bblk,
                          const float* __restrict__ gin, float* __restrict__ hist,
                          u16* __restrict__ zcur, float* __restrict__ gout) {
    __shared__ float red[4];
    const int tid = threadIdx.x;
    const int t8 = (blockIdx.x * 256 + tid) * 8;   // elem index in [o][b][n]
    const int o = t8 >> 20;                        // BAN = 2^20, block-uniform
    const int n = t8 & (AN - 1);
    const int io = t8 & (BAN - 1);                 // b*AN + n
    const float thr = THRESHOLD * (float)BAN;
    float s[8] = {0.f, 0.f, 0.f, 0.f, 0.f, 0.f, 0.f, 0.f};
#pragma unroll
    for (int i = 0; i < 4; ++i) {
        if (!(gin[i] > thr)) continue;
        const float4* p = (const float4*)(zacc + ((size_t)i * 4 + o) * BAN + io);
        const float4 x0 = p[0], x1 = p[1];
        const float4* bb = (const float4*)(bblk + (size_t)(o * 4 + i) * AN + n);
        const float4 b0 = bb[0], b1 = bb[1];
        s[0] += x0.x + b0.x; s[1] += x0.y + b0.y; s[2] += x0.z + b0.z; s[3] += x0.w + b0.w;
        s[4] += x1.x + b1.x; s[5] += x1.y + b1.y; s[6] += x1.z + b1.z; s[7] += x1.w + b1.w;
    }
    float4 h0, h1;
    uint4 zb;
    const float z0 = tanhf(s[0]), z1 = tanhf(s[1]), z2 = tanhf(s[2]), z3 = tanhf(s[3]);
    const float z4 = tanhf(s[4]), z5 = tanhf(s[5]), z6 = tanhf(s[6]), z7 = tanhf(s[7]);
    float asum = fabsf(z0) + fabsf(z1) + fabsf(z2) + fabsf(z3)
               + fabsf(z4) + fabsf(z5) + fabsf(z6) + fabsf(z7);
    h0.x = z0; h0.y = z1; h0.z = z2; h0.w = z3;
    h1.x = z4; h1.y = z5; h1.z = z6; h1.w = z7;
    zb.x = (unsigned)f2bf(z0) | ((unsigned)f2bf(z1) << 16);
    zb.y = (unsigned)f2bf(z2) | ((unsigned)f2bf(z3) << 16);
    zb.z = (unsigned)f2bf(z4) | ((unsigned)f2bf(z5) << 16);
    zb.w = (unsigned)f2bf(z6) | ((unsigned)f2bf(z7) << 16);
    ((float4*)(hist + t8))[0] = h0;
    ((float4*)(hist + t8))[1] = h1;
    *((uint4*)(zcur + t8)) = zb;
    for (int off = 32; off > 0; off >>= 1) asum += __shfl_down(asum, off, 64);
    if ((tid & 63) == 0) red[tid >> 6] = asum;
    __syncthreads();
    if (tid == 0) atomicAdd(&gout[o], red[0] + red[1] + red[2] + red[3]);
}

// ---- scatter Z[a,b,n] -> Zflat[b, area_idx[a,n]] (bf16) ----
__global__ void k_scatter(const u16* __restrict__ z4, const int* __restrict__ aidx,
                          u16* __restrict__ zflat) {
    const int i = blockIdx.x * 256 + threadIdx.x;  // over 4*512*2048 = 2^22
    const int n = i & (AN - 1);
    const int bb = (i >> 11) & (BATCH - 1);
    const int a = i >> 20;
    const int j = aidx[a * AN + n];
    zflat[(size_t)bb * NTOT + j] = z4[i];
}

// ---- logits += Zflat @ Ow^T (split-K=8, atomic f32) ----
__global__ void k_out(const u16* __restrict__ zflat, const u16* __restrict__ owbf,
                      float* __restrict__ out) {
    __shared__ __align__(16) u16 smemA[8192];
    __shared__ __align__(16) u16 smemB[8192];
    floatx4 acc[4][4] = {};
    const int nb = blockIdx.x, mb = blockIdx.y, ks = blockIdx.z;
    gemm_db(zflat + (size_t)mb * 128 * NTOT + ks * 1024, NTOT,
            owbf + (size_t)nb * 128 * NTOT + ks * 1024, NTOT, 1024,
            smemA, smemB, acc);
    const int tid = threadIdx.x, lane = tid & 63, quad = lane >> 4, l15 = lane & 15;
    const int wm = ((tid >> 7) & 1) * 64, wn = ((tid >> 6) & 1) * 64;
#pragma unroll
    for (int mt = 0; mt < 4; ++mt)
#pragma unroll
        for (int nt = 0; nt < 4; ++nt)
#pragma unroll
            for (int r = 0; r < 4; ++r) {
                const int row = mb * 128 + wm + mt * 16 + quad * 4 + r;
                const int col = nb * 128 + wn + nt * 16 + l15;
                atomicAdd(&out[(size_t)row * NCLS + col], acc[mt][nt][r]);
            }
}

extern "C" void kernel_launch(void* const* d_in, const int* in_sizes, int n_in,
                              void* d_out, int out_size, void* d_ws, size_t ws_size,
                              hipStream_t stream) {
    (void)in_sizes; (void)n_in; (void)out_size; (void)ws_size;
    const float* x    = (const float*)d_in[0];
    const float* Rw   = (const float*)d_in[1];
    const float* rb   = (const float*)d_in[2];
    const float* Wb   = (const float*)d_in[3];
    const float* bblk = (const float*)d_in[4];
    const float* mask = (const float*)d_in[5];
    const float* Ow   = (const float*)d_in[6];
    const float* Ob   = (const float*)d_in[7];
    const int*   aidx = (const int*)d_in[8];

    float* out  = (float*)d_out;
    float* hist = out + (size_t)BATCH * NCLS;  // history: [5, 4, 512, 2048]

    char* ws = (char*)d_ws;
    size_t off = 0;
    auto alloc = [&](size_t bytes) -> char* {
        char* p = ws + off;
        off += (bytes + 255) & ~(size_t)255;
        return p;
    };
    u16* weffbf = (u16*)alloc((size_t)16 * AN * AN * 2);      // 128 MiB
    // zacc: [4 i][4 o][512][2048] f32 split-K slices = 67.1 MiB.
    // Aliased over rwbf/owbf/zflat (live only OUTSIDE the tick loop).
    float* zacc = (float*)alloc((size_t)16 * BAN * 4);        // 67.1 MiB
    u16* rwbf  = (u16*)zacc;                                  // [0, 16 MiB)
    u16* owbf  = (u16*)((char*)zacc + ((size_t)16 << 20));    // [16, 32 MiB)
    u16* zflat = (u16*)((char*)zacc + ((size_t)32 << 20));    // [32, 40 MiB)
    u16* xbf    = (u16*)alloc((size_t)BATCH * DIN * 2);       // 1 MiB
    u16* zb0    = (u16*)alloc((size_t)NUM_AREAS * BAN * 2);   // 8 MiB
    u16* zb1    = (u16*)alloc((size_t)NUM_AREAS * BAN * 2);   // 8 MiB
    float* gacc = (float*)alloc(32 * 4);                      // [5][4] sums of |Z|
    u16* zb[2]  = { zb0, zb1 };

    k_init<<<(BATCH * NCLS + 255) / 256, 256, 0, stream>>>(Ob, out, gacc);
    k_cvt<<<(BATCH * DIN / 8) / 256, 256, 0, stream>>>(x, xbf, BATCH * DIN / 8);
    k_cvt<<<(NTOT * DIN / 8) / 256, 256, 0, stream>>>(Rw, rwbf, NTOT * DIN / 8);
    k_weff<<<4096, 256, 0, stream>>>(Wb, mask, weffbf);

    dim3 g1(64, 4);
    k_enc<<<g1, 256, 0, stream>>>(xbf, rwbf, rb, hist, zb[0], gacc);
    dim3 gmm(64, 4, 4);
    for (int t = 1; t <= 4; ++t) {
        k_tick_mm<<<gmm, 256, 0, stream>>>(zb[(t + 1) & 1], weffbf,
                                           gacc + (t - 1) * 4, zacc);
        k_tick_ep<<<2048, 256, 0, stream>>>(zacc, bblk, gacc + (t - 1) * 4,
                                            hist + (size_t)t * NUM_AREAS * BAN,
                                            zb[t & 1], gacc + t * 4);
    }
    // owbf/zflat alias zacc -> convert Ow only after ticks are done
    k_cvt<<<(NCLS * NTOT / 8) / 256, 256, 0, stream>>>(Ow, owbf, NCLS * NTOT / 8);
    // final Z is in zb[0] after 4 ticks
    k_scatter<<<(NUM_AREAS * BAN) / 256, 256, 0, stream>>>(zb[0], aidx, zflat);
    k_out<<<dim3(8, 4, 8), 256, 0, stream>>>(zflat, owbf, out);
}

// Round 3
// 1102.249 us; speedup vs baseline: 1.0326x; 1.0326x over previous
//
#include <hip/hip_runtime.h>
#include <stdint.h>

typedef unsigned short u16;
typedef float floatx4 __attribute__((ext_vector_type(4)));
typedef __bf16 bf16x8 __attribute__((ext_vector_type(8)));
typedef float f32x4v __attribute__((ext_vector_type(4)));
typedef unsigned u32x4v __attribute__((ext_vector_type(4)));

#define NUM_AREAS 4
#define AN 2048
#define NTOT 8192
#define BATCH 512
#define DIN 1024
#define NCLS 1024
#define THRESHOLD 0.05f
#define BAN (BATCH * AN)  // 1048576 elems per (area) slab

__device__ __forceinline__ u16 f2bf(float f) {
    union { float f; unsigned u; } v; v.f = f;
    unsigned r = v.u + 0x7fffu + ((v.u >> 16) & 1u);  // RNE
    return (u16)(r >> 16);
}

__device__ __forceinline__ void load_lds16(const u16* g, u16* l) {
    __builtin_amdgcn_global_load_lds((const __attribute__((address_space(1))) void*)g,
                                     (__attribute__((address_space(3))) void*)l,
                                     16, 0, 0);
}

// ---- 128x128 bf16 GEMM core, depth-1 double-buffered (T3 minimal 2-phase) ----
// C += A[128,klen] * B[128,klen]^T. A row-major lda, Bm row-major ldb.
// 256 threads = 4 waves in 2x2; each wave 64x64 via 4x4 tiles of 16x16x32 MFMA.
// ORDER MATTERS: ds_read(buf) FIRST, then issue stage(buf^1), then MFMA.
// If stage precedes the ds_reads, hipcc cannot prove no LDS alias and drains
// vmcnt(0) before the ds_reads, killing the pipeline (round-2 lesson).
__device__ __forceinline__ void gemm_db(const u16* __restrict__ A, int lda,
                                        const u16* __restrict__ Bm, int ldb,
                                        int klen, u16* sA, u16* sB,
                                        floatx4 acc[4][4]) {
    const int tid = threadIdx.x;
    const int t8 = tid * 8;
    const int lane = tid & 63;
    const int quad = lane >> 4;
    const int l15 = lane & 15;
    const int wm = ((tid >> 7) & 1) * 64;
    const int wn = ((tid >> 6) & 1) * 64;
    const int r0 = t8 >> 5;          // rows 0..63 (q=0), +64 for q=1
    const int kk = t8 & 31;          // k offset within 32-wide tile
    const int nst = klen >> 5;

    auto stage = [&](int buf, int k0) {
        const int bo = buf << 12;    // buffer offset in elems (4096)
        load_lds16(A + (size_t)r0 * lda + (k0 + kk), sA + bo + t8);
        load_lds16(Bm + (size_t)r0 * ldb + (k0 + kk), sB + bo + t8);
        load_lds16(A + (size_t)(r0 + 64) * lda + (k0 + kk), sA + bo + 2048 + t8);
        load_lds16(Bm + (size_t)(r0 + 64) * ldb + (k0 + kk), sB + bo + 2048 + t8);
    };

    stage(0, 0);
    __syncthreads();                 // drain prologue stage
    int buf = 0;
    for (int t = 0; t < nst; ++t) {
        const int bo = buf << 12;
        bf16x8 av[4], bv[4];
#pragma unroll
        for (int i = 0; i < 4; ++i)
            av[i] = *(const bf16x8*)(sA + bo + (wm + i * 16 + l15) * 32 + quad * 8);
#pragma unroll
        for (int i = 0; i < 4; ++i)
            bv[i] = *(const bf16x8*)(sB + bo + (wn + i * 16 + l15) * 32 + quad * 8);
        if (t + 1 < nst) stage(buf ^ 1, (t + 1) << 5);  // prefetch AFTER ds_reads
#pragma unroll
        for (int mt = 0; mt < 4; ++mt)
#pragma unroll
            for (int nt = 0; nt < 4; ++nt)
                acc[mt][nt] = __builtin_amdgcn_mfma_f32_16x16x32_bf16(av[mt], bv[nt], acc[mt][nt], 0, 0, 0);
        __syncthreads();             // vmcnt(0): prefetch had MFMA-phase + 3 peer blocks to land
        buf ^= 1;
    }
}

// ---- init: logits = Ob broadcast, gate accumulators = 0 ----
__global__ void k_init(const float* __restrict__ Ob, float* __restrict__ out,
                       float* __restrict__ gacc) {
    const int i = blockIdx.x * 256 + threadIdx.x;
    if (i < BATCH * NCLS) out[i] = Ob[i & (NCLS - 1)];
    if (i < 32) gacc[i] = 0.f;
}

// ---- f32 -> bf16 bulk convert (8 elems/thread) ----
__global__ void k_cvt(const float* __restrict__ src, u16* __restrict__ dst, int n8) {
    const int i = blockIdx.x * 256 + threadIdx.x;
    if (i >= n8) return;
    const float4 x0 = ((const float4*)src)[2 * i];
    const float4 x1 = ((const float4*)src)[2 * i + 1];
    uint4 o;
    o.x = (unsigned)f2bf(x0.x) | ((unsigned)f2bf(x0.y) << 16);
    o.y = (unsigned)f2bf(x0.z) | ((unsigned)f2bf(x0.w) << 16);
    o.z = (unsigned)f2bf(x1.x) | ((unsigned)f2bf(x1.y) << 16);
    o.w = (unsigned)f2bf(x1.z) | ((unsigned)f2bf(x1.w) << 16);
    ((uint4*)dst)[i] = o;
}

// ---- Weff = W * clamp(mask,0,1) -> bf16, 16 elems/thread ----
// 8 loads issued back-to-back, kept live via asm (forces MLP; round-2 had
// VGPR=24 -> compiler serialized loads -> latency-bound at 2.5 TB/s).
__global__ void k_weff(const float* __restrict__ W, const float* __restrict__ mask,
                       u16* __restrict__ dst) {
    const int i = blockIdx.x * 256 + threadIdx.x;   // 16 elems/thread, one-shot
    const f32x4v* wp = (const f32x4v*)W + (size_t)4 * i;
    const f32x4v* mp = (const f32x4v*)mask + (size_t)4 * i;
    f32x4v w0 = wp[0], w1 = wp[1], w2 = wp[2], w3 = wp[3];
    f32x4v m0 = mp[0], m1 = mp[1], m2 = mp[2], m3 = mp[3];
    // keep all 8 loads live simultaneously -> 128B in flight per thread
    asm volatile("" :: "v"(w0), "v"(w1), "v"(w2), "v"(w3),
                       "v"(m0), "v"(m1), "v"(m2), "v"(m3));
    #define CL(m) fminf(fmaxf((m), 0.f), 1.f)
    #define PK(wa, ma, wb, mb) ((unsigned)f2bf((wa) * CL(ma)) | ((unsigned)f2bf((wb) * CL(mb)) << 16))
    u32x4v o0, o1;
    o0[0] = PK(w0[0], m0[0], w0[1], m0[1]);
    o0[1] = PK(w0[2], m0[2], w0[3], m0[3]);
    o0[2] = PK(w1[0], m1[0], w1[1], m1[1]);
    o0[3] = PK(w1[2], m1[2], w1[3], m1[3]);
    o1[0] = PK(w2[0], m2[0], w2[1], m2[1]);
    o1[1] = PK(w2[2], m2[2], w2[3], m2[3]);
    o1[2] = PK(w3[0], m3[0], w3[1], m3[1]);
    o1[3] = PK(w3[2], m3[2], w3[3], m3[3]);
    #undef PK
    #undef CL
    u32x4v* dp = (u32x4v*)dst + (size_t)2 * i;
    dp[0] = o0;
    dp[1] = o1;
}

// ---- encoder: Z0 = tanh(x @ Rw^T + rb), write hist[0], z0(bf16), gate sums ----
__global__ void k_enc(const u16* __restrict__ xbf, const u16* __restrict__ rwbf,
                      const float* __restrict__ rb, float* __restrict__ hist0,
                      u16* __restrict__ z0, float* __restrict__ gacc) {
    __shared__ __align__(16) u16 smemA[8192];
    __shared__ __align__(16) u16 smemB[8192];
    __shared__ float red[4];
    floatx4 acc[4][4] = {};
    const int mb = blockIdx.y, nb = blockIdx.x;
    gemm_db(xbf + (size_t)mb * 128 * DIN, DIN,
            rwbf + (size_t)nb * 128 * DIN, DIN, DIN, smemA, smemB, acc);
    const int tid = threadIdx.x, lane = tid & 63, quad = lane >> 4, l15 = lane & 15;
    const int wm = ((tid >> 7) & 1) * 64, wn = ((tid >> 6) & 1) * 64;
    const int cbase = nb * 128;
    const int area = cbase >> 11;
    float asum = 0.f;
#pragma unroll
    for (int nt = 0; nt < 4; ++nt) {
        const int col = cbase + wn + nt * 16 + l15;
        const int n = col & (AN - 1);
        const float bias = rb[col];
#pragma unroll
        for (int mt = 0; mt < 4; ++mt) {
#pragma unroll
            for (int r = 0; r < 4; ++r) {
                const int row = mb * 128 + wm + mt * 16 + quad * 4 + r;
                const float z = tanhf(acc[mt][nt][r] + bias);
                asum += fabsf(z);
                const size_t idx = (size_t)area * BAN + (size_t)row * AN + n;
                hist0[idx] = z;
                z0[idx] = f2bf(z);
            }
        }
    }
    for (int off = 32; off > 0; off >>= 1) asum += __shfl_down(asum, off, 64);
    if (lane == 0) red[tid >> 6] = asum;
    __syncthreads();
    if (tid == 0) atomicAdd(&gacc[area], red[0] + red[1] + red[2] + red[3]);
}

// ---- tick GEMM, split-K over input areas: zacc[i][o] = Z_prev[i] @ Weff[o,i]^T ----
// grid (64 nb, 4 mb, 4 i) = 1024 blocks -> 4 blocks/CU, all co-resident
__global__ void k_tick_mm(const u16* __restrict__ zprev, const u16* __restrict__ weff,
                          const float* __restrict__ gin, float* __restrict__ zacc) {
    __shared__ __align__(16) u16 smemA[8192];
    __shared__ __align__(16) u16 smemB[8192];
    const int nb = blockIdx.x, mb = blockIdx.y, i = blockIdx.z;
    const float thr = THRESHOLD * (float)BAN;  // gate on mean|Z| -> compare sums
    if (!(gin[i] > thr)) return;               // block-uniform; stale slice never read
    floatx4 acc[4][4] = {};
    const int cbase = nb * 128;
    const int o = cbase >> 11;
    const int nbase = cbase & (AN - 1);
    gemm_db(zprev + (size_t)i * BAN + (size_t)mb * 128 * AN, AN,
            weff + ((size_t)(o * 4 + i) * AN + nbase) * AN, AN, AN,
            smemA, smemB, acc);
    float* __restrict__ dst = zacc + ((size_t)i * 4 + o) * BAN;
    const int tid = threadIdx.x, lane = tid & 63, quad = lane >> 4, l15 = lane & 15;
    const int wm = ((tid >> 7) & 1) * 64, wn = ((tid >> 6) & 1) * 64;
#pragma unroll
    for (int nt = 0; nt < 4; ++nt) {
        const int n = nbase + wn + nt * 16 + l15;
#pragma unroll
        for (int mt = 0; mt < 4; ++mt) {
#pragma unroll
            for (int r = 0; r < 4; ++r) {
                const int row = mb * 128 + wm + mt * 16 + quad * 4 + r;
                dst[(size_t)row * AN + n] = acc[mt][nt][r];
            }
        }
    }
}

// ---- tick epilogue: Z = tanh(sum_i gate[i]*zacc[i][o] + sum_i gate[i]*b[o,i]) ----
__global__ void k_tick_ep(const float* __restrict__ zacc, const float* __restrict__ bblk,
                          const float* __restrict__ gin, float* __restrict__ hist,
                          u16* __restrict__ zcur, float* __restrict__ gout) {
    __shared__ float red[4];
    const int tid = threadIdx.x;
    const int t8 = (blockIdx.x * 256 + tid) * 8;   // elem index in [o][b][n]
    const int o = t8 >> 20;                        // BAN = 2^20, block-uniform
    const int n = t8 & (AN - 1);
    const int io = t8 & (BAN - 1);                 // b*AN + n
    const float thr = THRESHOLD * (float)BAN;
    float s[8] = {0.f, 0.f, 0.f, 0.f, 0.f, 0.f, 0.f, 0.f};
#pragma unroll
    for (int i = 0; i < 4; ++i) {
        if (!(gin[i] > thr)) continue;
        const float4* p = (const float4*)(zacc + ((size_t)i * 4 + o) * BAN + io);
        const float4 x0 = p[0], x1 = p[1];
        const float4* bb = (const float4*)(bblk + (size_t)(o * 4 + i) * AN + n);
        const float4 b0 = bb[0], b1 = bb[1];
        s[0] += x0.x + b0.x; s[1] += x0.y + b0.y; s[2] += x0.z + b0.z; s[3] += x0.w + b0.w;
        s[4] += x1.x + b1.x; s[5] += x1.y + b1.y; s[6] += x1.z + b1.z; s[7] += x1.w + b1.w;
    }
    float4 h0, h1;
    uint4 zb;
    const float z0 = tanhf(s[0]), z1 = tanhf(s[1]), z2 = tanhf(s[2]), z3 = tanhf(s[3]);
    const float z4 = tanhf(s[4]), z5 = tanhf(s[5]), z6 = tanhf(s[6]), z7 = tanhf(s[7]);
    float asum = fabsf(z0) + fabsf(z1) + fabsf(z2) + fabsf(z3)
               + fabsf(z4) + fabsf(z5) + fabsf(z6) + fabsf(z7);
    h0.x = z0; h0.y = z1; h0.z = z2; h0.w = z3;
    h1.x = z4; h1.y = z5; h1.z = z6; h1.w = z7;
    zb.x = (unsigned)f2bf(z0) | ((unsigned)f2bf(z1) << 16);
    zb.y = (unsigned)f2bf(z2) | ((unsigned)f2bf(z3) << 16);
    zb.z = (unsigned)f2bf(z4) | ((unsigned)f2bf(z5) << 16);
    zb.w = (unsigned)f2bf(z6) | ((unsigned)f2bf(z7) << 16);
    ((float4*)(hist + t8))[0] = h0;
    ((float4*)(hist + t8))[1] = h1;
    *((uint4*)(zcur + t8)) = zb;
    for (int off = 32; off > 0; off >>= 1) asum += __shfl_down(asum, off, 64);
    if ((tid & 63) == 0) red[tid >> 6] = asum;
    __syncthreads();
    if (tid == 0) atomicAdd(&gout[o], red[0] + red[1] + red[2] + red[3]);
}

// ---- scatter Z[a,b,n] -> Zflat[b, area_idx[a,n]] (bf16) ----
__global__ void k_scatter(const u16* __restrict__ z4, const int* __restrict__ aidx,
                          u16* __restrict__ zflat) {
    const int i = blockIdx.x * 256 + threadIdx.x;  // over 4*512*2048 = 2^22
    const int n = i & (AN - 1);
    const int bb = (i >> 11) & (BATCH - 1);
    const int a = i >> 20;
    const int j = aidx[a * AN + n];
    zflat[(size_t)bb * NTOT + j] = z4[i];
}

// ---- logits += Zflat @ Ow^T (split-K=8, atomic f32) ----
__global__ void k_out(const u16* __restrict__ zflat, const u16* __restrict__ owbf,
                      float* __restrict__ out) {
    __shared__ __align__(16) u16 smemA[8192];
    __shared__ __align__(16) u16 smemB[8192];
    floatx4 acc[4][4] = {};
    const int nb = blockIdx.x, mb = blockIdx.y, ks = blockIdx.z;
    gemm_db(zflat + (size_t)mb * 128 * NTOT + ks * 1024, NTOT,
            owbf + (size_t)nb * 128 * NTOT + ks * 1024, NTOT, 1024,
            smemA, smemB, acc);
    const int tid = threadIdx.x, lane = tid & 63, quad = lane >> 4, l15 = lane & 15;
    const int wm = ((tid >> 7) & 1) * 64, wn = ((tid >> 6) & 1) * 64;
#pragma unroll
    for (int mt = 0; mt < 4; ++mt)
#pragma unroll
        for (int nt = 0; nt < 4; ++nt)
#pragma unroll
            for (int r = 0; r < 4; ++r) {
                const int row = mb * 128 + wm + mt * 16 + quad * 4 + r;
                const int col = nb * 128 + wn + nt * 16 + l15;
                atomicAdd(&out[(size_t)row * NCLS + col], acc[mt][nt][r]);
            }
}

extern "C" void kernel_launch(void* const* d_in, const int* in_sizes, int n_in,
                              void* d_out, int out_size, void* d_ws, size_t ws_size,
                              hipStream_t stream) {
    (void)in_sizes; (void)n_in; (void)out_size; (void)ws_size;
    const float* x    = (const float*)d_in[0];
    const float* Rw   = (const float*)d_in[1];
    const float* rb   = (const float*)d_in[2];
    const float* Wb   = (const float*)d_in[3];
    const float* bblk = (const float*)d_in[4];
    const float* mask = (const float*)d_in[5];
    const float* Ow   = (const float*)d_in[6];
    const float* Ob   = (const float*)d_in[7];
    const int*   aidx = (const int*)d_in[8];

    float* out  = (float*)d_out;
    float* hist = out + (size_t)BATCH * NCLS;  // history: [5, 4, 512, 2048]

    char* ws = (char*)d_ws;
    size_t off = 0;
    auto alloc = [&](size_t bytes) -> char* {
        char* p = ws + off;
        off += (bytes + 255) & ~(size_t)255;
        return p;
    };
    u16* weffbf = (u16*)alloc((size_t)16 * AN * AN * 2);      // 128 MiB
    // zacc: [4 i][4 o][512][2048] f32 split-K slices = 67.1 MiB.
    // Aliased over rwbf/owbf/zflat (live only OUTSIDE the tick loop).
    float* zacc = (float*)alloc((size_t)16 * BAN * 4);        // 67.1 MiB
    u16* rwbf  = (u16*)zacc;                                  // [0, 16 MiB)
    u16* owbf  = (u16*)((char*)zacc + ((size_t)16 << 20));    // [16, 32 MiB)
    u16* zflat = (u16*)((char*)zacc + ((size_t)32 << 20));    // [32, 40 MiB)
    u16* xbf    = (u16*)alloc((size_t)BATCH * DIN * 2);       // 1 MiB
    u16* zb0    = (u16*)alloc((size_t)NUM_AREAS * BAN * 2);   // 8 MiB
    u16* zb1    = (u16*)alloc((size_t)NUM_AREAS * BAN * 2);   // 8 MiB
    float* gacc = (float*)alloc(32 * 4);                      // [5][4] sums of |Z|
    u16* zb[2]  = { zb0, zb1 };

    k_init<<<(BATCH * NCLS + 255) / 256, 256, 0, stream>>>(Ob, out, gacc);
    k_cvt<<<(BATCH * DIN / 8) / 256, 256, 0, stream>>>(x, xbf, BATCH * DIN / 8);
    k_cvt<<<(NTOT * DIN / 8) / 256, 256, 0, stream>>>(Rw, rwbf, NTOT * DIN / 8);
    k_weff<<<16384, 256, 0, stream>>>(Wb, mask, weffbf);      // 16 elems/thread

    dim3 g1(64, 4);
    k_enc<<<g1, 256, 0, stream>>>(xbf, rwbf, rb, hist, zb[0], gacc);
    dim3 gmm(64, 4, 4);
    for (int t = 1; t <= 4; ++t) {
        k_tick_mm<<<gmm, 256, 0, stream>>>(zb[(t + 1) & 1], weffbf,
                                           gacc + (t - 1) * 4, zacc);
        k_tick_ep<<<2048, 256, 0, stream>>>(zacc, bblk, gacc + (t - 1) * 4,
                                            hist + (size_t)t * NUM_AREAS * BAN,
                                            zb[t & 1], gacc + t * 4);
    }
    // owbf/zflat alias zacc -> convert Ow only after ticks are done
    k_cvt<<<(NCLS * NTOT / 8) / 256, 256, 0, stream>>>(Ow, owbf, NCLS * NTOT / 8);
    // final Z is in zb[0] after 4 ticks
    k_scatter<<<(NUM_AREAS * BAN) / 256, 256, 0, stream>>>(zb[0], aidx, zflat);
    k_out<<<dim3(8, 4, 8), 256, 0, stream>>>(zflat, owbf, out);
}